// Round 8
// baseline (14553.105 us; speedup 1.0000x reference)
//
#include <hip/hip_runtime.h>

#define BB 16384
#define GG 8192
#define DD 256
#define EPS   0.012f    // collection margin (>= 2B, B = bf16-RNE dot bound 2^-8)
#define EPS_R 0.0085f   // resolve re-filter margin (>= 2B + quant slack)
#define GSPLIT 8
#define GCH (GG / GSPLIT)     // 1024 groups per chunk
#define NSTEP (GCH / 128 * 8) // 8 g-tiles x 8 k-steps (BK=32) = 64
#define LCAP 12               // per-block per-row LDS candidate slots

typedef __attribute__((ext_vector_type(8))) short bf16x8;
typedef __attribute__((ext_vector_type(4))) float f32x4;
typedef unsigned int u32;
typedef unsigned short u16;
typedef unsigned long long u64;

__device__ __forceinline__ u32 enc_f32(float v) {
    u32 u = __float_as_uint(v);
    return (u & 0x80000000u) ? ~u : (u | 0x80000000u);
}
__device__ __forceinline__ float dec_f32(u32 e) {
    u32 u = (e & 0x80000000u) ? (e ^ 0x80000000u) : ~e;
    return __uint_as_float(u);   // dec(0) = NaN; fmaxf(x, NaN) = x
}

__device__ __forceinline__ void async_copy16(const void* g, u16* lds) {
    __builtin_amdgcn_global_load_lds(
        (const __attribute__((address_space(1))) void*)g,
        (__attribute__((address_space(3))) void*)lds, 16, 0, 0);
}

// ---------------- prep: fp32 -> bf16 (RNE) + inverse norms (4 rows/block) ----
__global__ __launch_bounds__(256)
void prep_kernel(const float* __restrict__ src, u16* __restrict__ dstb,
                 float* __restrict__ invn) {
    int wid = threadIdx.x >> 6, lane = threadIdx.x & 63;
    size_t r = (size_t)blockIdx.x * 4 + wid;
    float4 v = ((const float4*)(src + r * DD))[lane];
    float vv[4] = {v.x, v.y, v.z, v.w};
    u16 b[4];
    float ss = 0.f;
    #pragma unroll
    for (int k = 0; k < 4; ++k) {
        u32 u = __float_as_uint(vv[k]);
        b[k] = (u16)((u + 0x7fffu + ((u >> 16) & 1u)) >> 16);   // RNE bf16
        ss = fmaf(vv[k], vv[k], ss);
    }
    ushort4 pk; pk.x = b[0]; pk.y = b[1]; pk.z = b[2]; pk.w = b[3];
    ((ushort4*)(dstb + r * DD))[lane] = pk;
    #pragma unroll
    for (int off = 1; off < 64; off <<= 1) ss += __shfl_xor(ss, off);
    if (lane == 0) invn[r] = 1.0f / fmaxf(sqrtf(ss), 1e-12f);
}

// ---------------- GEMM: local LDS candidate lists, end-of-kernel flush ----
// grid (BB/128, GSPLIT). 128x128 tiles, BK=32, 4 waves (2x2), dbuf 32KB LDS,
// pair-line swizzle (validated r5, conflicts=0). 4 blocks/CU.
__global__ __launch_bounds__(256, 4)
void gemm_kernel(const u16* __restrict__ xb, const u16* __restrict__ gb,
                 const float* __restrict__ invx, const float* __restrict__ invg,
                 u32* __restrict__ amax, u32* __restrict__ ccnt,
                 u32* __restrict__ cand, int cs) {
    __shared__ u16 lds[2 * 8192];        // 32 KB tile double-buffer
    __shared__ u32 llist[128][LCAP];     // 6 KB per-row local candidates
    __shared__ u32 lcnt[128];            // 0.5 KB

    const int tid   = threadIdx.x;
    const int lane  = tid & 63;
    const int w     = tid >> 6;
    const int wr    = w >> 1, wc = w & 1;
    const int m0    = blockIdx.x * 128;
    const int cbase = blockIdx.y * GCH;

    // staging source permutation (LDS linear; stored slot8 = global_slot8 ^ line)
    const int s8g    = (lane & 7) ^ (lane >> 3);
    const int rowadd = 2 * (lane >> 3) + (s8g >> 2);
    const int koff   = (s8g & 3) * 8;

    const int fr = lane & 15;
    const int fq = lane >> 4;
    const int s8s = ((fr & 1) * 4 + fq) ^ (fr >> 1);  // swizzled read slot

    float ivx[16];
    #pragma unroll
    for (int i = 0; i < 4; ++i)
        #pragma unroll
        for (int r = 0; r < 4; ++r)
            ivx[i * 4 + r] = invx[m0 + wr * 64 + i * 16 + fq * 4 + r];

    float running[16];
    #pragma unroll
    for (int i = 0; i < 16; ++i) running[i] = -3.0e38f;

    f32x4 acc[4][4];
    #pragma unroll
    for (int i = 0; i < 4; ++i)
        #pragma unroll
        for (int j = 0; j < 4; ++j) acc[i][j] = (f32x4){0.f, 0.f, 0.f, 0.f};

    auto stage = [&](int buf, int gt, int k0) {
        #pragma unroll
        for (int q = 0; q < 2; ++q) {
            int R0 = w * 32 + q * 16;    // 16-row chunk = 8 swizzle lines
            async_copy16(xb + (size_t)(m0 + R0 + rowadd) * DD + k0 + koff,
                         &lds[buf * 8192 + R0 * 32]);
            async_copy16(gb + (size_t)(cbase + gt * 128 + R0 + rowadd) * DD + k0 + koff,
                         &lds[buf * 8192 + 4096 + R0 * 32]);
        }
    };

    stage(0, 0, 0);
    if (tid < 128) lcnt[tid] = 0;
    __syncthreads();

    int cur = 0;
    for (int s = 0; s < NSTEP; ++s) {
        const int gt = s >> 3;
        if (s < NSTEP - 1) stage(cur ^ 1, (s + 1) >> 3, ((s + 1) & 7) * 32);

        bf16x8 af[4], bf[4];
        #pragma unroll
        for (int i = 0; i < 4; ++i) {
            int lineA = wr * 32 + i * 8 + (fr >> 1);
            af[i] = *(const bf16x8*)&lds[cur * 8192 + lineA * 64 + s8s * 8];
            int lineB = wc * 32 + i * 8 + (fr >> 1);
            bf[i] = *(const bf16x8*)&lds[cur * 8192 + 4096 + lineB * 64 + s8s * 8];
        }
        #pragma unroll
        for (int i = 0; i < 4; ++i)
            #pragma unroll
            for (int j = 0; j < 4; ++j)
                acc[i][j] = __builtin_amdgcn_mfma_f32_16x16x32_bf16(
                    af[i], bf[j], acc[i][j], 0, 0, 0);

        if ((s & 7) == 7) {
            // ---- per-g-tile epilogue: LOCAL threshold only, no global reads ----
            const int g0 = cbase + gt * 128;
            float ivg4[4];
            #pragma unroll
            for (int j = 0; j < 4; ++j) ivg4[j] = invg[g0 + wc * 64 + j * 16 + fr];
            #pragma unroll
            for (int i = 0; i < 4; ++i) {
                #pragma unroll
                for (int r = 0; r < 4; ++r) {
                    float u0 = acc[i][0][r] * ivg4[0];
                    float u1 = acc[i][1][r] * ivg4[1];
                    float u2 = acc[i][2][r] * ivg4[2];
                    float u3 = acc[i][3][r] * ivg4[3];
                    float sm = fmaxf(fmaxf(u0, u1), fmaxf(u2, u3));
                    #pragma unroll
                    for (int off = 1; off < 16; off <<= 1)
                        sm = fmaxf(sm, __shfl_xor(sm, off));   // strip max over fr
                    const int rowl = wr * 64 + i * 16 + fq * 4 + r;
                    const float iv = ivx[i * 4 + r];
                    float mc = sm * iv;
                    if (fr == 0)                                // fire & forget
                        atomicMax(&amax[m0 + rowl], enc_f32(mc));
                    float runv = fmaxf(running[i * 4 + r], mc); // block-monotone
                    running[i * 4 + r] = runv;
                    float thr = runv - EPS;
                    #pragma unroll
                    for (int j = 0; j < 4; ++j) {
                        float v = (j == 0 ? u0 : j == 1 ? u1 : j == 2 ? u2 : u3) * iv;
                        if (v >= thr) {
                            u32 c = atomicAdd(&lcnt[rowl], 1u);  // LDS atomic
                            if (c < LCAP) {
                                float vq = fminf(fmaxf((v + 1.0f) * 32768.0f, 0.0f),
                                                 65535.0f);
                                llist[rowl][c] = ((u32)vq << 16) |
                                    (u32)(g0 + wc * 64 + j * 16 + fr);
                            }
                        }
                    }
                }
            }
            #pragma unroll
            for (int i = 0; i < 4; ++i)
                #pragma unroll
                for (int j = 0; j < 4; ++j) acc[i][j] = (f32x4){0.f, 0.f, 0.f, 0.f};
        }
        __syncthreads();
        cur ^= 1;
    }

    // ---- flush: filter local list vs (near-final) global max, append ----
    // By now amax is warm (all blocks publish per-tile); staleness only
    // lowers the threshold -> a few extra survivors, never a miss.
    if (tid < 128) {
        const int rowl = tid;
        const int row  = m0 + rowl;
        u32 lc = lcnt[rowl];
        if (lc > LCAP) {
            atomicOr(&ccnt[row], 0x40000000u);    // force exact fallback
        } else if (lc > 0) {
            u32 a = __hip_atomic_load(&amax[row], __ATOMIC_RELAXED,
                                      __HIP_MEMORY_SCOPE_AGENT);
            float thr = dec_f32(a) - EPS - 0.0001f;   // + quant slack
            u32 keep[LCAP]; int nk = 0;
            for (u32 c = 0; c < lc; ++c) {
                u32 e = llist[rowl][c];
                float qv = (float)(e >> 16) * (1.0f / 32768.0f) - 1.0f;
                if (qv >= thr) keep[nk++] = e;
            }
            if (nk > 0) {
                u32 base = atomicAdd(&ccnt[row], (u32)nk);
                for (int k = 0; k < nk; ++k)
                    if (base + (u32)k < (u32)cs)
                        cand[(size_t)row * cs + base + k] = keep[k];
            }
        }
    }
}

// ---------------- resolve: filter by final max, exact eval survivors ----------
__global__ __launch_bounds__(256)
void resolve_kernel(const float* __restrict__ x, const float* __restrict__ gf,
                    const float* __restrict__ invg, const u32* __restrict__ amax,
                    const u32* __restrict__ ccnt, const u32* __restrict__ cand,
                    int cs, float* __restrict__ sums, float* __restrict__ counts) {
    __shared__ float xs[4][DD];
    int wid = threadIdx.x >> 6, lane = threadIdx.x & 63;
    int row = blockIdx.x * 4 + wid;
    float4 xv = ((const float4*)(x + (size_t)row * DD))[lane];
    ((float4*)xs[wid])[lane] = xv;   // wave-local staging (same-wave consume)

    u32 cnt = ccnt[row];
    float best = -3.0e38f; int bcol = GG - 1;

    bool fast = (cnt >= 1 && cnt <= (u32)cs);
    u32 e = 0; u64 mask = 0;
    if (fast) {
        float thr = dec_f32(amax[row]) - EPS_R;    // final approx max - margin
        e = (lane < (int)cnt) ? cand[(size_t)row * cs + lane] : 0u;
        float qv = (float)(e >> 16) * (1.0f / 32768.0f) - 1.0f;
        mask = __ballot((lane < (int)cnt) && (qv >= thr));
        if (mask == 0) fast = false;               // paranoia: never empty
    }

    if (fast) {
        while (mask) {
            int c = (int)(__ffsll((unsigned long long)mask) - 1);
            mask &= mask - 1;
            int col = __shfl((int)(e & 0xffffu), c);
            float4 gv = ((const float4*)(gf + (size_t)col * DD))[lane];
            float p = fmaf(xv.x, gv.x, fmaf(xv.y, gv.y,
                      fmaf(xv.z, gv.z, xv.w * gv.w)));
            #pragma unroll
            for (int off = 1; off < 64; off <<= 1) p += __shfl_xor(p, off);
            float v = p * invg[col];
            if (v > best || (v == best && col < bcol)) { best = v; bcol = col; }
        }
    } else {
        // overflow fallback: exact scan over all groups
        for (int col = lane; col < GG; col += 64) {
            const float4* gr = (const float4*)(gf + (size_t)col * DD);
            float s = 0.f;
            #pragma unroll 8
            for (int d = 0; d < 64; ++d) {
                float4 g4 = gr[d];
                s = fmaf(xs[wid][d * 4 + 0], g4.x, s);
                s = fmaf(xs[wid][d * 4 + 1], g4.y, s);
                s = fmaf(xs[wid][d * 4 + 2], g4.z, s);
                s = fmaf(xs[wid][d * 4 + 3], g4.w, s);
            }
            float v = s * invg[col];
            if (v > best || (v == best && col < bcol)) { best = v; bcol = col; }
        }
        #pragma unroll
        for (int off = 1; off < 64; off <<= 1) {
            float ov = __shfl_xor(best, off);
            int   oc = __shfl_xor(bcol, off);
            if (ov > best || (ov == best && oc < bcol)) { best = ov; bcol = oc; }
        }
    }
    // fused scatter-mean accumulation
    if (lane == 0) atomicAdd(&counts[bcol], 1.0f);
    float* sp = sums + (size_t)bcol * DD + lane * 4;
    atomicAdd(sp + 0, xv.x); atomicAdd(sp + 1, xv.y);
    atomicAdd(sp + 2, xv.z); atomicAdd(sp + 3, xv.w);
}

// ---------------- EMA finalize ----------------
__global__ __launch_bounds__(256)
void final_kernel(const float* __restrict__ gf, const float* __restrict__ sums,
                  const float* __restrict__ counts, float* __restrict__ out) {
    int i = blockIdx.x * 256 + threadIdx.x;
    int g = i >> 8;
    out[i] = 0.99f * gf[i] + 0.01f * (sums[i] / fmaxf(counts[g], 1.0f));
}

extern "C" void kernel_launch(void* const* d_in, const int* in_sizes, int n_in,
                              void* d_out, int out_size, void* d_ws, size_t ws_size,
                              hipStream_t stream) {
    const float* x  = (const float*)d_in[0];   // [16384, 256]
    const float* gf = (const float*)d_in[1];   // [8192, 256]
    float* out = (float*)d_out;

    char* ws = (char*)d_ws;
    u16*   xb     = (u16*)ws;                       // 8 MB (sums aliases later)
    u16*   gb     = (u16*)(ws + 8388608);           // 4 MB
    float* invx   = (float*)(ws + 12582912);        // 64 KB
    float* invg   = (float*)(ws + 12648448);        // 32 KB
    u32*   amax   = (u32*)  (ws + 12681216);        // 64 KB
    u32*   ccnt   = (u32*)  (ws + 12746752);        // 64 KB
    float* counts = (float*)(ws + 12812288);        // 32 KB
    u32*   cand   = (u32*)  (ws + 12845056);        // cs*64K bytes (dynamic)
    float* sums   = (float*)ws;                     // aliases xb (dead after gemm)

    size_t cand_off = 12845056;
    int cs = 4;
    if (ws_size > cand_off) {
        size_t slots = (ws_size - cand_off) / ((size_t)BB * 4);
        cs = (int)(slots > 64 ? 64 : slots);
        if (cs < 4) cs = 4;
    }

    // zero amax+ccnt+counts (contiguous 160 KB)
    hipMemsetAsync(amax, 0, 160 * 1024, stream);

    prep_kernel<<<BB / 4, 256, 0, stream>>>(x,  xb, invx);
    prep_kernel<<<GG / 4, 256, 0, stream>>>(gf, gb, invg);

    gemm_kernel<<<dim3(BB / 128, GSPLIT), 256, 0, stream>>>(
        xb, gb, invx, invg, amax, ccnt, cand, cs);

    hipMemsetAsync(sums, 0, 8388608, stream);       // xb dead; reuse as sums

    resolve_kernel<<<BB / 4, 256, 0, stream>>>(
        x, gf, invg, amax, ccnt, cand, cs, sums, counts);
    final_kernel<<<GG * DD / 256, 256, 0, stream>>>(gf, sums, counts, out);
}

// Round 9
// 630.496 us; speedup vs baseline: 23.0820x; 23.0820x over previous
//
#include <hip/hip_runtime.h>

#define BB 16384
#define GG 8192
#define DD 256
#define EPS   0.012f   // collection margin (>= 2B, B = bf16-RNE dot bound)
#define EPS_R 0.008f   // resolve re-filter margin vs final approx max
#define GSPLIT 8
#define GCH (GG / GSPLIT)     // 1024 groups per chunk
#define NSTEP (GCH / 128 * 8) // 8 g-tiles x 8 k-steps (BK=32) = 64

typedef __attribute__((ext_vector_type(8))) short bf16x8;
typedef __attribute__((ext_vector_type(4))) float f32x4;
typedef unsigned int u32;
typedef unsigned short u16;
typedef unsigned long long u64;

__device__ __forceinline__ u32 enc_f32(float v) {
    u32 u = __float_as_uint(v);
    return (u & 0x80000000u) ? ~u : (u | 0x80000000u);
}
__device__ __forceinline__ float dec_f32(u32 e) {
    u32 u = (e & 0x80000000u) ? (e ^ 0x80000000u) : ~e;
    return __uint_as_float(u);   // dec(0) = NaN; fmaxf(x, NaN) = x
}

__device__ __forceinline__ void async_copy16(const void* g, u16* lds) {
    __builtin_amdgcn_global_load_lds(
        (const __attribute__((address_space(1))) void*)g,
        (__attribute__((address_space(3))) void*)lds, 16, 0, 0);
}

// ---------------- prep: fp32 -> bf16 (RNE) + inverse norms (4 rows/block) ----
__global__ __launch_bounds__(256)
void prep_kernel(const float* __restrict__ src, u16* __restrict__ dstb,
                 float* __restrict__ invn) {
    int wid = threadIdx.x >> 6, lane = threadIdx.x & 63;
    size_t r = (size_t)blockIdx.x * 4 + wid;
    float4 v = ((const float4*)(src + r * DD))[lane];
    float vv[4] = {v.x, v.y, v.z, v.w};
    u16 b[4];
    float ss = 0.f;
    #pragma unroll
    for (int k = 0; k < 4; ++k) {
        u32 u = __float_as_uint(vv[k]);
        b[k] = (u16)((u + 0x7fffu + ((u >> 16) & 1u)) >> 16);   // RNE bf16
        ss = fmaf(vv[k], vv[k], ss);
    }
    ushort4 pk; pk.x = b[0]; pk.y = b[1]; pk.z = b[2]; pk.w = b[3];
    ((ushort4*)(dstb + r * DD))[lane] = pk;
    #pragma unroll
    for (int off = 1; off < 64; off <<= 1) ss += __shfl_xor(ss, off);
    if (lane == 0) invn[r] = 1.0f / fmaxf(sqrtf(ss), 1e-12f);
}

// ---------------- GEMM: G-chunk loop, BK=32, pair-line swizzle, collect ----
// grid (BB/128, GSPLIT). 128x128 tiles, 4 waves (2x2), dbuf 32KB LDS.
// Cross-block threshold sharing via atomicMax RETURN VALUES only (the sole
// coherent read across XCD L2s) — batched 8 per issue to overlap latency.
__global__ __launch_bounds__(256, 4)
void gemm_kernel(const u16* __restrict__ xb, const u16* __restrict__ gb,
                 const float* __restrict__ invx, const float* __restrict__ invg,
                 u32* __restrict__ amax, u32* __restrict__ ccnt,
                 u32* __restrict__ cand, int cs) {
    __shared__ u16 lds[2 * 8192];   // [buf][A 4096 | B 4096] shorts = 32 KB

    const int tid   = threadIdx.x;
    const int lane  = tid & 63;
    const int w     = tid >> 6;
    const int wr    = w >> 1, wc = w & 1;
    const int m0    = blockIdx.x * 128;
    const int cbase = blockIdx.y * GCH;

    // staging source permutation (validated r5: LDS linear, pair-line swizzle;
    // stored slot8 = global_slot8 ^ (line&7), line = row pair)
    const int s8g    = (lane & 7) ^ (lane >> 3);
    const int rowadd = 2 * (lane >> 3) + (s8g >> 2);
    const int koff   = (s8g & 3) * 8;

    const int fr = lane & 15;
    const int fq = lane >> 4;
    const int s8s = ((fr & 1) * 4 + fq) ^ (fr >> 1);  // swizzled read slot

    float ivx[16];
    #pragma unroll
    for (int i = 0; i < 4; ++i)
        #pragma unroll
        for (int r = 0; r < 4; ++r)
            ivx[i * 4 + r] = invx[m0 + wr * 64 + i * 16 + fq * 4 + r];

    float running[16];
    #pragma unroll
    for (int i = 0; i < 16; ++i) running[i] = -3.0e38f;

    f32x4 acc[4][4];
    #pragma unroll
    for (int i = 0; i < 4; ++i)
        #pragma unroll
        for (int j = 0; j < 4; ++j) acc[i][j] = (f32x4){0.f, 0.f, 0.f, 0.f};

    auto stage = [&](int buf, int gt, int k0) {
        #pragma unroll
        for (int q = 0; q < 2; ++q) {
            int R0 = w * 32 + q * 16;    // 16-row chunk = 8 swizzle lines
            async_copy16(xb + (size_t)(m0 + R0 + rowadd) * DD + k0 + koff,
                         &lds[buf * 8192 + R0 * 32]);
            async_copy16(gb + (size_t)(cbase + gt * 128 + R0 + rowadd) * DD + k0 + koff,
                         &lds[buf * 8192 + 4096 + R0 * 32]);
        }
    };

    stage(0, 0, 0);
    __syncthreads();

    int cur = 0;
    for (int s = 0; s < NSTEP; ++s) {
        const int gt = s >> 3;
        if (s < NSTEP - 1) stage(cur ^ 1, (s + 1) >> 3, ((s + 1) & 7) * 32);

        bf16x8 af[4], bf[4];
        #pragma unroll
        for (int i = 0; i < 4; ++i) {
            int lineA = wr * 32 + i * 8 + (fr >> 1);
            af[i] = *(const bf16x8*)&lds[cur * 8192 + lineA * 64 + s8s * 8];
            int lineB = wc * 32 + i * 8 + (fr >> 1);
            bf[i] = *(const bf16x8*)&lds[cur * 8192 + 4096 + lineB * 64 + s8s * 8];
        }
        #pragma unroll
        for (int i = 0; i < 4; ++i)
            #pragma unroll
            for (int j = 0; j < 4; ++j)
                acc[i][j] = __builtin_amdgcn_mfma_f32_16x16x32_bf16(
                    af[i], bf[j], acc[i][j], 0, 0, 0);

        if ((s & 7) == 7) {
            // ---- per-g-tile epilogue: batched atomicMax-with-return ----
            const int g0 = cbase + gt * 128;
            float ivg4[4];
            #pragma unroll
            for (int j = 0; j < 4; ++j) ivg4[j] = invg[g0 + wc * 64 + j * 16 + fr];

            #pragma unroll
            for (int half = 0; half < 2; ++half) {
                // phase A: strip maxes for 8 rows (pure VALU/shfl)
                float mcs[8];
                #pragma unroll
                for (int k = 0; k < 8; ++k) {
                    const int i = half * 2 + (k >> 2), r = k & 3;
                    float sm = fmaxf(fmaxf(acc[i][0][r] * ivg4[0],
                                           acc[i][1][r] * ivg4[1]),
                                     fmaxf(acc[i][2][r] * ivg4[2],
                                           acc[i][3][r] * ivg4[3]));
                    #pragma unroll
                    for (int off = 1; off < 16; off <<= 1)
                        sm = fmaxf(sm, __shfl_xor(sm, off));
                    mcs[k] = sm * ivx[i * 4 + r];
                }
                // phase B: 8 independent RMW round-trips, issued back-to-back
                u32 olds[8];
                if (fr == 0) {
                    #pragma unroll
                    for (int k = 0; k < 8; ++k) {
                        const int i = half * 2 + (k >> 2), r = k & 3;
                        const int row = m0 + wr * 64 + i * 16 + fq * 4 + r;
                        olds[k] = atomicMax(&amax[row], enc_f32(mcs[k]));
                    }
                }
                // phase C: broadcast, combine, collect
                #pragma unroll
                for (int k = 0; k < 8; ++k) {
                    const int i = half * 2 + (k >> 2), r = k & 3;
                    const int idx = i * 4 + r;
                    u32 ob = __shfl(olds[k], lane & 48);
                    float runv = fmaxf(fmaxf(running[idx], mcs[k]), dec_f32(ob));
                    running[idx] = runv;
                    const float thr = runv - EPS;
                    const float iv = ivx[idx];
                    const int row = m0 + wr * 64 + i * 16 + fq * 4 + r;
                    #pragma unroll
                    for (int j = 0; j < 4; ++j) {
                        float v = acc[i][j][r] * ivg4[j] * iv;
                        if (v >= thr) {
                            u32 c = atomicAdd(&ccnt[row], 1u);
                            if (c < (u32)cs) {
                                float vq = fminf(fmaxf((v + 1.0f) * 32768.0f, 0.0f),
                                                 65535.0f);
                                cand[(size_t)row * cs + c] =
                                    ((u32)vq << 16) |
                                    (u32)(g0 + wc * 64 + j * 16 + fr);
                            }
                        }
                    }
                }
            }
            #pragma unroll
            for (int i = 0; i < 4; ++i)
                #pragma unroll
                for (int j = 0; j < 4; ++j) acc[i][j] = (f32x4){0.f, 0.f, 0.f, 0.f};
        }
        __syncthreads();
        cur ^= 1;
    }
}

// ---------------- resolve: filter by final max, exact eval survivors ----------
__global__ __launch_bounds__(256)
void resolve_kernel(const float* __restrict__ x, const float* __restrict__ gf,
                    const float* __restrict__ invg, const u32* __restrict__ amax,
                    const u32* __restrict__ ccnt, const u32* __restrict__ cand,
                    int cs, float* __restrict__ sums, float* __restrict__ counts) {
    __shared__ float xs[4][DD];
    int wid = threadIdx.x >> 6, lane = threadIdx.x & 63;
    int row = blockIdx.x * 4 + wid;
    float4 xv = ((const float4*)(x + (size_t)row * DD))[lane];
    ((float4*)xs[wid])[lane] = xv;   // wave-local staging (same-wave consume)

    u32 cnt = ccnt[row];
    float best = -3.0e38f; int bcol = GG - 1;

    bool fast = (cnt >= 1 && cnt <= (u32)cs);
    u32 e = 0; u64 mask = 0;
    if (fast) {
        float thr = dec_f32(amax[row]) - EPS_R;    // final approx max - margin
        e = (lane < (int)cnt) ? cand[(size_t)row * cs + lane] : 0u;
        float qv = (float)(e >> 16) * (1.0f / 32768.0f) - 1.0f;
        mask = __ballot((lane < (int)cnt) && (qv >= thr));
        if (mask == 0) fast = false;               // paranoia: never empty
    }

    if (fast) {
        while (mask) {
            int c = (int)(__ffsll((unsigned long long)mask) - 1);
            mask &= mask - 1;
            int col = __shfl((int)(e & 0xffffu), c);
            float4 gv = ((const float4*)(gf + (size_t)col * DD))[lane];
            float p = fmaf(xv.x, gv.x, fmaf(xv.y, gv.y,
                      fmaf(xv.z, gv.z, xv.w * gv.w)));
            #pragma unroll
            for (int off = 1; off < 64; off <<= 1) p += __shfl_xor(p, off);
            float v = p * invg[col];
            if (v > best || (v == best && col < bcol)) { best = v; bcol = col; }
        }
    } else {
        // overflow fallback: exact scan over all groups
        for (int col = lane; col < GG; col += 64) {
            const float4* gr = (const float4*)(gf + (size_t)col * DD);
            float s = 0.f;
            #pragma unroll 8
            for (int d = 0; d < 64; ++d) {
                float4 g4 = gr[d];
                s = fmaf(xs[wid][d * 4 + 0], g4.x, s);
                s = fmaf(xs[wid][d * 4 + 1], g4.y, s);
                s = fmaf(xs[wid][d * 4 + 2], g4.z, s);
                s = fmaf(xs[wid][d * 4 + 3], g4.w, s);
            }
            float v = s * invg[col];
            if (v > best || (v == best && col < bcol)) { best = v; bcol = col; }
        }
        #pragma unroll
        for (int off = 1; off < 64; off <<= 1) {
            float ov = __shfl_xor(best, off);
            int   oc = __shfl_xor(bcol, off);
            if (ov > best || (ov == best && oc < bcol)) { best = ov; bcol = oc; }
        }
    }
    // fused scatter-mean accumulation
    if (lane == 0) atomicAdd(&counts[bcol], 1.0f);
    float* sp = sums + (size_t)bcol * DD + lane * 4;
    atomicAdd(sp + 0, xv.x); atomicAdd(sp + 1, xv.y);
    atomicAdd(sp + 2, xv.z); atomicAdd(sp + 3, xv.w);
}

// ---------------- EMA finalize ----------------
__global__ __launch_bounds__(256)
void final_kernel(const float* __restrict__ gf, const float* __restrict__ sums,
                  const float* __restrict__ counts, float* __restrict__ out) {
    int i = blockIdx.x * 256 + threadIdx.x;
    int g = i >> 8;
    out[i] = 0.99f * gf[i] + 0.01f * (sums[i] / fmaxf(counts[g], 1.0f));
}

extern "C" void kernel_launch(void* const* d_in, const int* in_sizes, int n_in,
                              void* d_out, int out_size, void* d_ws, size_t ws_size,
                              hipStream_t stream) {
    const float* x  = (const float*)d_in[0];   // [16384, 256]
    const float* gf = (const float*)d_in[1];   // [8192, 256]
    float* out = (float*)d_out;

    char* ws = (char*)d_ws;
    u16*   xb     = (u16*)ws;                       // 8 MB (sums aliases later)
    u16*   gb     = (u16*)(ws + 8388608);           // 4 MB
    float* invx   = (float*)(ws + 12582912);        // 64 KB
    float* invg   = (float*)(ws + 12648448);        // 32 KB
    u32*   amax   = (u32*)  (ws + 12681216);        // 64 KB
    u32*   ccnt   = (u32*)  (ws + 12746752);        // 64 KB
    float* counts = (float*)(ws + 12812288);        // 32 KB
    u32*   cand   = (u32*)  (ws + 12845056);        // cs*64K bytes (dynamic)
    float* sums   = (float*)ws;                     // aliases xb (dead after gemm)

    size_t cand_off = 12845056;
    int cs = 4;
    if (ws_size > cand_off) {
        size_t slots = (ws_size - cand_off) / ((size_t)BB * 4);
        cs = (int)(slots > 64 ? 64 : slots);
        if (cs < 4) cs = 4;
    }

    // zero amax+ccnt+counts (contiguous 160 KB)
    hipMemsetAsync(amax, 0, 160 * 1024, stream);

    prep_kernel<<<BB / 4, 256, 0, stream>>>(x,  xb, invx);
    prep_kernel<<<GG / 4, 256, 0, stream>>>(gf, gb, invg);

    gemm_kernel<<<dim3(BB / 128, GSPLIT), 256, 0, stream>>>(
        xb, gb, invx, invg, amax, ccnt, cand, cs);

    hipMemsetAsync(sums, 0, 8388608, stream);       // xb dead; reuse as sums

    resolve_kernel<<<BB / 4, 256, 0, stream>>>(
        x, gf, invg, amax, ccnt, cand, cs, sums, counts);
    final_kernel<<<GG * DD / 256, 256, 0, stream>>>(gf, sums, counts, out);
}

// Round 10
// 492.351 us; speedup vs baseline: 29.5584x; 1.2806x over previous
//
#include <hip/hip_runtime.h>

#define BB 16384
#define GG 8192
#define DD 256
#define EPS 0.012f     // collection margin (>= 2B, B = bf16-RNE dot bound 2^-8)
#define GSPLIT 8
#define GCH (GG / GSPLIT)     // 1024 groups per chunk
#define NSTEP (GCH / 128 * 8) // 8 g-tiles x 8 k-steps (BK=32) = 64

typedef __attribute__((ext_vector_type(8))) short bf16x8;
typedef __attribute__((ext_vector_type(4))) float f32x4;
typedef unsigned int u32;
typedef unsigned short u16;
typedef unsigned long long u64;

__device__ __forceinline__ u32 enc_f32(float v) {
    u32 u = __float_as_uint(v);
    return (u & 0x80000000u) ? ~u : (u | 0x80000000u);
}
__device__ __forceinline__ float dec_f32(u32 e) {
    u32 u = (e & 0x80000000u) ? (e ^ 0x80000000u) : ~e;
    return __uint_as_float(u);   // dec(0) = NaN; fmaxf(x, NaN) = x
}

__device__ __forceinline__ void async_copy16(const void* g, u16* lds) {
    __builtin_amdgcn_global_load_lds(
        (const __attribute__((address_space(1))) void*)g,
        (__attribute__((address_space(3))) void*)lds, 16, 0, 0);
}

// ---------------- prep: fp32 -> bf16 (RNE) + inverse norms (4 rows/block) ----
__global__ __launch_bounds__(256)
void prep_kernel(const float* __restrict__ src, u16* __restrict__ dstb,
                 float* __restrict__ invn) {
    int wid = threadIdx.x >> 6, lane = threadIdx.x & 63;
    size_t r = (size_t)blockIdx.x * 4 + wid;
    float4 v = ((const float4*)(src + r * DD))[lane];
    float vv[4] = {v.x, v.y, v.z, v.w};
    u16 b[4];
    float ss = 0.f;
    #pragma unroll
    for (int k = 0; k < 4; ++k) {
        u32 u = __float_as_uint(vv[k]);
        b[k] = (u16)((u + 0x7fffu + ((u >> 16) & 1u)) >> 16);   // RNE bf16
        ss = fmaf(vv[k], vv[k], ss);
    }
    ushort4 pk; pk.x = b[0]; pk.y = b[1]; pk.z = b[2]; pk.w = b[3];
    ((ushort4*)(dstb + r * DD))[lane] = pk;
    #pragma unroll
    for (int off = 1; off < 64; off <<= 1) ss += __shfl_xor(ss, off);
    if (lane == 0) invn[r] = 1.0f / fmaxf(sqrtf(ss), 1e-12f);
}

// ---------------- GEMM: G-chunk loop, BK=32, pair-line swizzle, collect ----
// grid (BB/128, GSPLIT). 128x128 tiles, 4 waves (2x2), dbuf 32KB LDS.
// Cross-block threshold sharing via atomicMax RETURN VALUES only (the sole
// coherent read across XCD L2s) — batched 8 per issue to overlap latency.
// Candidates: u16 column index only; resolve exact-evals them all.
__global__ __launch_bounds__(256, 4)
void gemm_kernel(const u16* __restrict__ xb, const u16* __restrict__ gb,
                 const float* __restrict__ invx, const float* __restrict__ invg,
                 u32* __restrict__ amax, u32* __restrict__ ccnt,
                 u16* __restrict__ cand, int cs) {
    __shared__ u16 lds[2 * 8192];   // [buf][A 4096 | B 4096] shorts = 32 KB

    const int tid   = threadIdx.x;
    const int lane  = tid & 63;
    const int w     = tid >> 6;
    const int wr    = w >> 1, wc = w & 1;
    const int m0    = blockIdx.x * 128;
    const int cbase = blockIdx.y * GCH;

    // staging source permutation (validated r5: LDS linear, pair-line swizzle;
    // stored slot8 = global_slot8 ^ (line&7), line = row pair)
    const int s8g    = (lane & 7) ^ (lane >> 3);
    const int rowadd = 2 * (lane >> 3) + (s8g >> 2);
    const int koff   = (s8g & 3) * 8;

    const int fr = lane & 15;
    const int fq = lane >> 4;
    const int s8s = ((fr & 1) * 4 + fq) ^ (fr >> 1);  // swizzled read slot

    float ivx[16];
    #pragma unroll
    for (int i = 0; i < 4; ++i)
        #pragma unroll
        for (int r = 0; r < 4; ++r)
            ivx[i * 4 + r] = invx[m0 + wr * 64 + i * 16 + fq * 4 + r];

    float running[16];
    #pragma unroll
    for (int i = 0; i < 16; ++i) running[i] = -3.0e38f;

    f32x4 acc[4][4];
    #pragma unroll
    for (int i = 0; i < 4; ++i)
        #pragma unroll
        for (int j = 0; j < 4; ++j) acc[i][j] = (f32x4){0.f, 0.f, 0.f, 0.f};

    auto stage = [&](int buf, int gt, int k0) {
        #pragma unroll
        for (int q = 0; q < 2; ++q) {
            int R0 = w * 32 + q * 16;    // 16-row chunk = 8 swizzle lines
            async_copy16(xb + (size_t)(m0 + R0 + rowadd) * DD + k0 + koff,
                         &lds[buf * 8192 + R0 * 32]);
            async_copy16(gb + (size_t)(cbase + gt * 128 + R0 + rowadd) * DD + k0 + koff,
                         &lds[buf * 8192 + 4096 + R0 * 32]);
        }
    };

    stage(0, 0, 0);
    __syncthreads();

    int cur = 0;
    for (int s = 0; s < NSTEP; ++s) {
        const int gt = s >> 3;
        if (s < NSTEP - 1) stage(cur ^ 1, (s + 1) >> 3, ((s + 1) & 7) * 32);

        bf16x8 af[4], bf[4];
        #pragma unroll
        for (int i = 0; i < 4; ++i) {
            int lineA = wr * 32 + i * 8 + (fr >> 1);
            af[i] = *(const bf16x8*)&lds[cur * 8192 + lineA * 64 + s8s * 8];
            int lineB = wc * 32 + i * 8 + (fr >> 1);
            bf[i] = *(const bf16x8*)&lds[cur * 8192 + 4096 + lineB * 64 + s8s * 8];
        }
        #pragma unroll
        for (int i = 0; i < 4; ++i)
            #pragma unroll
            for (int j = 0; j < 4; ++j)
                acc[i][j] = __builtin_amdgcn_mfma_f32_16x16x32_bf16(
                    af[i], bf[j], acc[i][j], 0, 0, 0);

        if ((s & 7) == 7) {
            // ---- per-g-tile epilogue: batched atomicMax-with-return ----
            const int g0 = cbase + gt * 128;
            float ivg4[4];
            #pragma unroll
            for (int j = 0; j < 4; ++j) ivg4[j] = invg[g0 + wc * 64 + j * 16 + fr];

            #pragma unroll
            for (int half = 0; half < 2; ++half) {
                // phase A: strip maxes for 8 rows (pure VALU/shfl)
                float mcs[8];
                #pragma unroll
                for (int k = 0; k < 8; ++k) {
                    const int i = half * 2 + (k >> 2), r = k & 3;
                    float sm = fmaxf(fmaxf(acc[i][0][r] * ivg4[0],
                                           acc[i][1][r] * ivg4[1]),
                                     fmaxf(acc[i][2][r] * ivg4[2],
                                           acc[i][3][r] * ivg4[3]));
                    #pragma unroll
                    for (int off = 1; off < 16; off <<= 1)
                        sm = fmaxf(sm, __shfl_xor(sm, off));
                    mcs[k] = sm * ivx[i * 4 + r];
                }
                // phase B: 8 independent RMW round-trips, issued back-to-back
                u32 olds[8];
                if (fr == 0) {
                    #pragma unroll
                    for (int k = 0; k < 8; ++k) {
                        const int i = half * 2 + (k >> 2), r = k & 3;
                        const int row = m0 + wr * 64 + i * 16 + fq * 4 + r;
                        olds[k] = atomicMax(&amax[row], enc_f32(mcs[k]));
                    }
                }
                // phase C: broadcast, combine, collect
                #pragma unroll
                for (int k = 0; k < 8; ++k) {
                    const int i = half * 2 + (k >> 2), r = k & 3;
                    const int idx = i * 4 + r;
                    u32 ob = __shfl(olds[k], lane & 48);
                    float runv = fmaxf(fmaxf(running[idx], mcs[k]), dec_f32(ob));
                    running[idx] = runv;
                    const float thr = runv - EPS;
                    const float iv = ivx[idx];
                    const int row = m0 + wr * 64 + i * 16 + fq * 4 + r;
                    #pragma unroll
                    for (int j = 0; j < 4; ++j) {
                        float v = acc[i][j][r] * ivg4[j] * iv;
                        if (v >= thr) {
                            u32 c = atomicAdd(&ccnt[row], 1u);
                            if (c < (u32)cs)
                                cand[(size_t)row * cs + c] =
                                    (u16)(g0 + wc * 64 + j * 16 + fr);
                        }
                    }
                }
            }
            #pragma unroll
            for (int i = 0; i < 4; ++i)
                #pragma unroll
                for (int j = 0; j < 4; ++j) acc[i][j] = (f32x4){0.f, 0.f, 0.f, 0.f};
        }
        __syncthreads();
        cur ^= 1;
    }
}

// ---------------- resolve: exact fp32 eval of ALL candidates + fused scatter --
__global__ __launch_bounds__(256)
void resolve_kernel(const float* __restrict__ x, const float* __restrict__ gf,
                    const float* __restrict__ invg,
                    const u32* __restrict__ ccnt, const u16* __restrict__ cand,
                    int cs, float* __restrict__ sums, float* __restrict__ counts) {
    __shared__ float xs[4][DD];
    int wid = threadIdx.x >> 6, lane = threadIdx.x & 63;
    int row = blockIdx.x * 4 + wid;
    float4 xv = ((const float4*)(x + (size_t)row * DD))[lane];
    ((float4*)xs[wid])[lane] = xv;   // wave-local staging (same-wave consume)

    u32 cnt = ccnt[row];
    float best = -3.0e38f; int bcol = GG - 1;

    if (cnt >= 1 && cnt <= (u32)cs) {
        // fast path: exact-eval every collected candidate (winner is among them)
        int my0 = (lane < (int)cnt) ? (int)cand[(size_t)row * cs + lane] : 0;
        int my1 = (lane + 64 < (int)cnt) ? (int)cand[(size_t)row * cs + lane + 64] : 0;
        for (u32 c = 0; c < cnt; ++c) {
            int col = __shfl((c < 64u) ? my0 : my1, (int)(c & 63u));
            float4 gv = ((const float4*)(gf + (size_t)col * DD))[lane];
            float p = fmaf(xv.x, gv.x, fmaf(xv.y, gv.y,
                      fmaf(xv.z, gv.z, xv.w * gv.w)));
            #pragma unroll
            for (int off = 1; off < 64; off <<= 1) p += __shfl_xor(p, off);
            float v = p * invg[col];
            if (v > best || (v == best && col < bcol)) { best = v; bcol = col; }
        }
    } else {
        // overflow fallback (vanishingly rare): exact scan over all groups
        for (int col = lane; col < GG; col += 64) {
            const float4* gr = (const float4*)(gf + (size_t)col * DD);
            float s = 0.f;
            #pragma unroll 8
            for (int d = 0; d < 64; ++d) {
                float4 g4 = gr[d];
                s = fmaf(xs[wid][d * 4 + 0], g4.x, s);
                s = fmaf(xs[wid][d * 4 + 1], g4.y, s);
                s = fmaf(xs[wid][d * 4 + 2], g4.z, s);
                s = fmaf(xs[wid][d * 4 + 3], g4.w, s);
            }
            float v = s * invg[col];
            if (v > best || (v == best && col < bcol)) { best = v; bcol = col; }
        }
        #pragma unroll
        for (int off = 1; off < 64; off <<= 1) {
            float ov = __shfl_xor(best, off);
            int   oc = __shfl_xor(bcol, off);
            if (ov > best || (ov == best && oc < bcol)) { best = ov; bcol = oc; }
        }
    }
    // fused scatter-mean accumulation
    if (lane == 0) atomicAdd(&counts[bcol], 1.0f);
    float* sp = sums + (size_t)bcol * DD + lane * 4;
    atomicAdd(sp + 0, xv.x); atomicAdd(sp + 1, xv.y);
    atomicAdd(sp + 2, xv.z); atomicAdd(sp + 3, xv.w);
}

// ---------------- EMA finalize ----------------
__global__ __launch_bounds__(256)
void final_kernel(const float* __restrict__ gf, const float* __restrict__ sums,
                  const float* __restrict__ counts, float* __restrict__ out) {
    int i = blockIdx.x * 256 + threadIdx.x;
    int g = i >> 8;
    out[i] = 0.99f * gf[i] + 0.01f * (sums[i] / fmaxf(counts[g], 1.0f));
}

extern "C" void kernel_launch(void* const* d_in, const int* in_sizes, int n_in,
                              void* d_out, int out_size, void* d_ws, size_t ws_size,
                              hipStream_t stream) {
    const float* x  = (const float*)d_in[0];   // [16384, 256]
    const float* gf = (const float*)d_in[1];   // [8192, 256]
    float* out = (float*)d_out;

    char* ws = (char*)d_ws;
    u16*   xb     = (u16*)ws;                       // 8 MB (sums aliases later)
    u16*   gb     = (u16*)(ws + 8388608);           // 4 MB
    float* invx   = (float*)(ws + 12582912);        // 64 KB
    float* invg   = (float*)(ws + 12648448);        // 32 KB
    u32*   amax   = (u32*)  (ws + 12681216);        // 64 KB
    u32*   ccnt   = (u32*)  (ws + 12746752);        // 64 KB
    float* counts = (float*)(ws + 12812288);        // 32 KB
    u16*   cand   = (u16*)  (ws + 12845056);        // cs*32K bytes (dynamic)
    float* sums   = (float*)ws;                     // aliases xb (dead after gemm)

    // candidate slots per row (u16 each), sized to available workspace
    size_t cand_off = 12845056;
    int cs = 8;
    if (ws_size > cand_off) {
        size_t slots = (ws_size - cand_off) / ((size_t)BB * 2);
        cs = (int)(slots > 128 ? 128 : slots);
        if (cs < 8) cs = 8;
    }

    // zero amax+ccnt+counts (contiguous 160 KB)
    hipMemsetAsync(amax, 0, 160 * 1024, stream);

    prep_kernel<<<BB / 4, 256, 0, stream>>>(x,  xb, invx);
    prep_kernel<<<GG / 4, 256, 0, stream>>>(gf, gb, invg);

    gemm_kernel<<<dim3(BB / 128, GSPLIT), 256, 0, stream>>>(
        xb, gb, invx, invg, amax, ccnt, cand, cs);

    hipMemsetAsync(sums, 0, 8388608, stream);       // xb dead; reuse as sums

    resolve_kernel<<<BB / 4, 256, 0, stream>>>(
        x, gf, invg, ccnt, cand, cs, sums, counts);
    final_kernel<<<GG * DD / 256, 256, 0, stream>>>(gf, sums, counts, out);
}